// Round 3
// baseline (7868.774 us; speedup 1.0000x reference)
//
#include <hip/hip_runtime.h>
#include <hip/hip_bf16.h>

// Sinkhorn entropic OT (reg=1, 100 iters), persistent-kernel edition.
//   Z = 2*log2e*(x.yT) fp16 [32MiB], ZT likewise. Cores telescope:
//   f: fcore_i = LOG2A - log2 sum_j 2^(gcore_j + Z_ij)
//   g: gcore_j = LOG2A - log2 sum_i 2^(fcore_i + ZT_ji)
//   init gcore_j = LOG2A - ay_j
//   out = ln2/(N*D) * [ sum_i 2^(fcore-php)*(fcore+ax-LOG2A) + sum_j (gcore+ay-LOG2A) ]
// One kernel, 256 blocks x 1024 threads, custom device-scope grid barrier.

#define N 4096
#define D 1024
#define L2E 1.4426950408889634f
#define LOG2A (-12.0f)
#define NBLK 256
#define NITER 100

typedef unsigned short u16;
typedef _Float16 f16;
typedef __attribute__((ext_vector_type(8))) short bf16x8;
typedef __attribute__((ext_vector_type(8))) _Float16 f16x8;
typedef __attribute__((ext_vector_type(4))) float f32x4;

static __device__ inline u16 f2bf(float f) {
  unsigned u = __float_as_uint(f);
  unsigned r = (u + 0x7FFFu + ((u >> 16) & 1u)) >> 16;
  return (u16)r;
}

static __device__ inline void gload_lds16(const void* g, void* l) {
  __builtin_amdgcn_global_load_lds(
      (const __attribute__((address_space(1))) void*)g,
      (__attribute__((address_space(3))) void*)l, 16, 0, 0);
}

// ---- prep: row sum-of-squares + fp32->bf16 + ax/ay/gcore0 + barrier reset
__global__ __launch_bounds__(256) void prep_kernel(
    const float* __restrict__ x, const float* __restrict__ y,
    u16* __restrict__ xb, u16* __restrict__ yb,
    float* __restrict__ ax, float* __restrict__ ay, float* __restrict__ g0,
    unsigned* __restrict__ bar)
{
  int rb = blockIdx.x;
  bool isY = rb >= N;
  int row = isY ? rb - N : rb;
  const float4* src = (const float4*)((isY ? y : x) + (size_t)row * D);
  u16* dst = (isY ? yb : xb) + (size_t)row * D;
  int t = threadIdx.x;

  if (rb == 0 && t == 0)
    __hip_atomic_store(&bar[0], 0u, __ATOMIC_RELAXED, __HIP_MEMORY_SCOPE_AGENT);

  float4 v = src[t];
  float ss = v.x * v.x + v.y * v.y + v.z * v.z + v.w * v.w;
  ushort4 h;
  h.x = f2bf(v.x); h.y = f2bf(v.y); h.z = f2bf(v.z); h.w = f2bf(v.w);
  ((ushort4*)dst)[t] = h;

  #pragma unroll
  for (int o = 1; o < 64; o <<= 1) ss += __shfl_xor(ss, o, 64);
  __shared__ float sred[4];
  if ((t & 63) == 0) sred[t >> 6] = ss;
  __syncthreads();
  if (t == 0) {
    float a = (sred[0] + sred[1] + sred[2] + sred[3]) * L2E;
    if (isY) { ay[row] = a; g0[row] = LOG2A - a; }
    else     { ax[row] = a; }
  }
}

// ---- GEMM: Z[i][j] = fp16(2*log2e*(A_i . B_j)), bf16 MFMA 128x128 tile
__global__ __launch_bounds__(256) void gemm_s(
    const u16* __restrict__ A, const u16* __restrict__ B, f16* __restrict__ out)
{
  __shared__ u16 As[128 * 64];
  __shared__ u16 Bs[128 * 64];
  const int t = threadIdx.x;
  const int lane = t & 63, w = t >> 6;
  const int wm = w >> 1, wn = w & 1;
  const int i0 = blockIdx.y * 128, j0 = blockIdx.x * 128;

  f32x4 acc[4][4] = {};

  for (int k0 = 0; k0 < D; k0 += 64) {
    #pragma unroll
    for (int q = 0; q < 4; ++q) {
      int lin = q * 256 + t;
      int row = lin >> 3, c8 = lin & 7;
      int cs = c8 ^ (row & 7);
      const u16* ga = A + (size_t)(i0 + row) * D + k0 + cs * 8;
      const u16* gb = B + (size_t)(j0 + row) * D + k0 + cs * 8;
      gload_lds16(ga, ((char*)As) + q * 4096 + w * 1024);
      gload_lds16(gb, ((char*)Bs) + q * 4096 + w * 1024);
    }
    __syncthreads();
    #pragma unroll
    for (int kk = 0; kk < 2; ++kk) {
      bf16x8 af[4], bfr[4];
      const int g = lane >> 4;
      #pragma unroll
      for (int fm = 0; fm < 4; ++fm) {
        int r = wm * 64 + fm * 16 + (lane & 15);
        af[fm] = *(const bf16x8*)(((const char*)As) + r * 128 + (((kk * 4 + g) ^ (r & 7)) * 16));
      }
      #pragma unroll
      for (int fn = 0; fn < 4; ++fn) {
        int r = wn * 64 + fn * 16 + (lane & 15);
        bfr[fn] = *(const bf16x8*)(((const char*)Bs) + r * 128 + (((kk * 4 + g) ^ (r & 7)) * 16));
      }
      #pragma unroll
      for (int fm = 0; fm < 4; ++fm)
        #pragma unroll
        for (int fn = 0; fn < 4; ++fn)
          acc[fm][fn] = __builtin_amdgcn_mfma_f32_16x16x32_bf16(af[fm], bfr[fn], acc[fm][fn], 0, 0, 0);
    }
    __syncthreads();
  }

  const float TWO_L2E = 2.0f * L2E;
  #pragma unroll
  for (int fm = 0; fm < 4; ++fm)
    #pragma unroll
    for (int fn = 0; fn < 4; ++fn) {
      int gj = j0 + wn * 64 + fn * 16 + (lane & 15);
      #pragma unroll
      for (int r = 0; r < 4; ++r) {
        int gi = i0 + wm * 64 + fm * 16 + (lane >> 4) * 4 + r;
        out[(size_t)gi * N + gj] = (f16)(TWO_L2E * acc[fm][fn][r]);
      }
    }
}

// ---- device-scope sense-reversing grid barrier (thread 0 per block)
static __device__ inline void gridbar(unsigned* bar) {
  __syncthreads();
  if (threadIdx.x == 0) {
    unsigned g = __hip_atomic_load(&bar[1], __ATOMIC_RELAXED, __HIP_MEMORY_SCOPE_AGENT);
    unsigned a = __hip_atomic_fetch_add(&bar[0], 1u, __ATOMIC_ACQ_REL, __HIP_MEMORY_SCOPE_AGENT);
    if (a == NBLK - 1) {
      __hip_atomic_store(&bar[0], 0u, __ATOMIC_RELAXED, __HIP_MEMORY_SCOPE_AGENT);
      __hip_atomic_fetch_add(&bar[1], 1u, __ATOMIC_RELEASE, __HIP_MEMORY_SCOPE_AGENT);
    } else {
      while (__hip_atomic_load(&bar[1], __ATOMIC_ACQUIRE, __HIP_MEMORY_SCOPE_AGENT) == g)
        __builtin_amdgcn_s_sleep(2);
    }
  }
  __syncthreads();
}

// ---- one LSE phase: vout[row] = LOG2A - log2 sum_j 2^(vin_j + M[row][j])
// block handles 16 rows; wave w: quarter q=w>>2, rows rg=w&3 -> 4 rows.
static __device__ inline void lse_phase(
    const f16* __restrict__ M, const float* __restrict__ vin,
    float* __restrict__ vout, int blk, float* ulds, float2* part)
{
  const int t = threadIdx.x;
  const int w = t >> 6, lane = t & 63;
  const int q = w >> 2, rg = w & 3;

  // issue Z loads first (hide L3 latency under staging + sync)
  f16x8 zr[4][2];
  #pragma unroll
  for (int rr = 0; rr < 4; ++rr) {
    const f16x8* zp = (const f16x8*)(M + (size_t)(blk * 16 + rg * 4 + rr) * N + q * 1024 + lane * 16);
    zr[rr][0] = zp[0];
    zr[rr][1] = zp[1];
  }

  // stage vin into LDS, transposed within each 1024-col quarter:
  // col = q*1024 + l*16 + k  ->  ulds[q*1024 + k*64 + l]
  {
    float4 val = ((const float4*)vin)[t];
    #pragma unroll
    for (int j = 0; j < 4; ++j) {
      int col = 4 * t + j;
      int qq = col >> 10, r = col & 1023;
      ulds[qq * 1024 + (r & 15) * 64 + (r >> 4)] = ((const float*)&val)[j];
    }
  }
  __syncthreads();

  float uu[16];
  #pragma unroll
  for (int k = 0; k < 16; ++k) uu[k] = ulds[q * 1024 + k * 64 + lane];

  #pragma unroll
  for (int rr = 0; rr < 4; ++rr) {
    float vv[16];
    #pragma unroll
    for (int k = 0; k < 8; ++k) {
      vv[k]     = uu[k]     + (float)zr[rr][0][k];
      vv[8 + k] = uu[8 + k] + (float)zr[rr][1][k];
    }
    float m = vv[0];
    #pragma unroll
    for (int k = 1; k < 16; ++k) m = fmaxf(m, vv[k]);
    #pragma unroll
    for (int o = 1; o < 64; o <<= 1) m = fmaxf(m, __shfl_xor(m, o, 64));
    float s = 0.0f;
    #pragma unroll
    for (int k = 0; k < 16; ++k) s += exp2f(vv[k] - m);
    #pragma unroll
    for (int o = 1; o < 64; o <<= 1) s += __shfl_xor(s, o, 64);
    if (lane == 0) part[(rg * 4 + rr) * 4 + q] = make_float2(m, s);
  }
  __syncthreads();
  if (t < 16) {
    float2 p0 = part[t * 4 + 0], p1 = part[t * 4 + 1], p2 = part[t * 4 + 2], p3 = part[t * 4 + 3];
    float M0 = fmaxf(fmaxf(p0.x, p1.x), fmaxf(p2.x, p3.x));
    float S0 = p0.y * exp2f(p0.x - M0) + p1.y * exp2f(p1.x - M0)
             + p2.y * exp2f(p2.x - M0) + p3.y * exp2f(p3.x - M0);
    vout[blk * 16 + t] = -(M0 + log2f(S0)) + LOG2A;
  }
}

// ---- persistent Sinkhorn loop + finalize
__global__ __launch_bounds__(1024, 4) void sinkhorn_persist(
    const f16* __restrict__ Z, const f16* __restrict__ ZT,
    const float* __restrict__ ax, const float* __restrict__ ay,
    float* __restrict__ fcore, float* __restrict__ gcore, float* __restrict__ php,
    unsigned* __restrict__ bar, float* __restrict__ out)
{
  __shared__ float ulds[4096];
  __shared__ float2 part[64];
  __shared__ float sred[16];
  const int blk = blockIdx.x;

  for (int it = 0; it < NITER; ++it) {
    lse_phase(Z, gcore, fcore, blk, ulds, part);
    gridbar(bar);
    lse_phase(ZT, fcore, gcore, blk, ulds, part);
    gridbar(bar);
  }
  lse_phase(Z, gcore, php, blk, ulds, part);   // extra f-phase -> row marginals
  gridbar(bar);

  if (blk == 0) {
    const int t = threadIdx.x;
    float acc = 0.0f;
    #pragma unroll
    for (int rep = 0; rep < 4; ++rep) {
      int i = rep * 1024 + t;
      float fc = fcore[i];
      acc += exp2f(fc - php[i]) * (fc + ax[i] - LOG2A);
      acc += gcore[i] + ay[i] - LOG2A;
    }
    #pragma unroll
    for (int o = 1; o < 64; o <<= 1) acc += __shfl_xor(acc, o, 64);
    if ((t & 63) == 0) sred[t >> 6] = acc;
    __syncthreads();
    if (t == 0) {
      float tot = 0.0f;
      #pragma unroll
      for (int k = 0; k < 16; ++k) tot += sred[k];
      const float LN2 = 0.6931471805599453f;
      out[0] = tot * (LN2 / ((float)N * (float)D));
    }
  }
}

extern "C" void kernel_launch(void* const* d_in, const int* in_sizes, int n_in,
                              void* d_out, int out_size, void* d_ws, size_t ws_size,
                              hipStream_t stream) {
  const float* x = (const float*)d_in[0];
  const float* y = (const float*)d_in[1];
  float* out = (float*)d_out;
  char* ws = (char*)d_ws;

  const size_t SZ_Z  = (size_t)N * N * sizeof(f16);   // 32 MiB
  const size_t SZ_BF = (size_t)N * D * sizeof(u16);   // 8 MiB
  const size_t SZ_V  = (size_t)N * sizeof(float);     // 16 KiB

  f16* Z   = (f16*)(ws);
  f16* ZT  = (f16*)(ws + SZ_Z);
  u16* xb  = (u16*)(ws + 2 * SZ_Z);
  u16* yb  = (u16*)(ws + 2 * SZ_Z + SZ_BF);
  char* vb = ws + 2 * SZ_Z + 2 * SZ_BF;
  float* ax    = (float*)(vb + 0 * SZ_V);
  float* ay    = (float*)(vb + 1 * SZ_V);
  float* fcore = (float*)(vb + 2 * SZ_V);
  float* gcore = (float*)(vb + 3 * SZ_V);
  float* php   = (float*)(vb + 4 * SZ_V);
  unsigned* bar = (unsigned*)(vb + 5 * SZ_V);

  prep_kernel<<<2 * N, 256, 0, stream>>>(x, y, xb, yb, ax, ay, gcore, bar);

  dim3 gg(N / 128, N / 128, 1);
  gemm_s<<<gg, 256, 0, stream>>>(xb, yb, Z);
  gemm_s<<<gg, 256, 0, stream>>>(yb, xb, ZT);

  sinkhorn_persist<<<NBLK, 1024, 0, stream>>>(Z, ZT, ax, ay, fcore, gcore, php, bar, out);
}

// Round 4
// 5101.570 us; speedup vs baseline: 1.5424x; 1.5424x over previous
//
#include <hip/hip_runtime.h>
#include <hip/hip_bf16.h>

// Sinkhorn entropic OT (reg=1, 100 iters), persistent kernel + flag-array barrier.
//   Z = 2*log2e*(x.yT) fp16 [32MiB], ZT likewise. Cores telescope:
//   f: fcore_i = LOG2A - log2 sum_j 2^(gcore_j + Z_ij)
//   g: gcore_j = LOG2A - log2 sum_i 2^(fcore_i + ZT_ji)
//   init gcore_j = LOG2A - ay_j
//   out = ln2/(N*D) * [ sum_i 2^(fcore-php)*(fcore+ax-LOG2A) + sum_j (gcore+ay-LOG2A) ]
// Cross-block traffic (fcore/gcore/slots) via relaxed AGENT-scope atomics (sc1,
// bypasses non-coherent L2, NO acquire-invalidate so Z/ZT stay L2-resident).

#define N 4096
#define D 1024
#define L2E 1.4426950408889634f
#define LOG2A (-12.0f)
#define NBLK 256
#define NPHASE 201   // 100*(f,g) + final f

typedef unsigned short u16;
typedef _Float16 f16;
typedef __attribute__((ext_vector_type(8))) short bf16x8;
typedef __attribute__((ext_vector_type(8))) _Float16 f16x8;
typedef __attribute__((ext_vector_type(4))) float f32x4;

#define ALOAD(p)     __hip_atomic_load((p), __ATOMIC_RELAXED, __HIP_MEMORY_SCOPE_AGENT)
#define ASTORE(p, v) __hip_atomic_store((p), (v), __ATOMIC_RELAXED, __HIP_MEMORY_SCOPE_AGENT)

static __device__ inline u16 f2bf(float f) {
  unsigned u = __float_as_uint(f);
  unsigned r = (u + 0x7FFFu + ((u >> 16) & 1u)) >> 16;
  return (u16)r;
}

static __device__ inline void gload_lds16(const void* g, void* l) {
  __builtin_amdgcn_global_load_lds(
      (const __attribute__((address_space(1))) void*)g,
      (__attribute__((address_space(3))) void*)l, 16, 0, 0);
}

// ---- prep: row sum-of-squares + fp32->bf16 + ax/ay/gcore0 + slot reset
__global__ __launch_bounds__(256) void prep_kernel(
    const float* __restrict__ x, const float* __restrict__ y,
    u16* __restrict__ xb, u16* __restrict__ yb,
    float* __restrict__ ax, float* __restrict__ ay, float* __restrict__ g0,
    unsigned* __restrict__ slots)
{
  int rb = blockIdx.x;
  bool isY = rb >= N;
  int row = isY ? rb - N : rb;
  const float4* src = (const float4*)((isY ? y : x) + (size_t)row * D);
  u16* dst = (isY ? yb : xb) + (size_t)row * D;
  int t = threadIdx.x;

  if (rb == 0) ASTORE(&slots[t], 0u);   // 256 slots reset every call (replay-safe)

  float4 v = src[t];
  float ss = v.x * v.x + v.y * v.y + v.z * v.z + v.w * v.w;
  ushort4 h;
  h.x = f2bf(v.x); h.y = f2bf(v.y); h.z = f2bf(v.z); h.w = f2bf(v.w);
  ((ushort4*)dst)[t] = h;

  #pragma unroll
  for (int o = 1; o < 64; o <<= 1) ss += __shfl_xor(ss, o, 64);
  __shared__ float sred[4];
  if ((t & 63) == 0) sred[t >> 6] = ss;
  __syncthreads();
  if (t == 0) {
    float a = (sred[0] + sred[1] + sred[2] + sred[3]) * L2E;
    if (isY) { ay[row] = a; g0[row] = LOG2A - a; }
    else     { ax[row] = a; }
  }
}

// ---- GEMM: Z[i][j] = fp16(2*log2e*(A_i . B_j)), bf16 MFMA 128x128 tile
__global__ __launch_bounds__(256) void gemm_s(
    const u16* __restrict__ A, const u16* __restrict__ B, f16* __restrict__ out)
{
  __shared__ u16 As[128 * 64];
  __shared__ u16 Bs[128 * 64];
  const int t = threadIdx.x;
  const int lane = t & 63, w = t >> 6;
  const int wm = w >> 1, wn = w & 1;
  const int i0 = blockIdx.y * 128, j0 = blockIdx.x * 128;

  f32x4 acc[4][4] = {};

  for (int k0 = 0; k0 < D; k0 += 64) {
    #pragma unroll
    for (int q = 0; q < 4; ++q) {
      int lin = q * 256 + t;
      int row = lin >> 3, c8 = lin & 7;
      int cs = c8 ^ (row & 7);
      gload_lds16(A + (size_t)(i0 + row) * D + k0 + cs * 8, ((char*)As) + q * 4096 + w * 1024);
      gload_lds16(B + (size_t)(j0 + row) * D + k0 + cs * 8, ((char*)Bs) + q * 4096 + w * 1024);
    }
    __syncthreads();
    #pragma unroll
    for (int kk = 0; kk < 2; ++kk) {
      bf16x8 af[4], bfr[4];
      const int g = lane >> 4;
      #pragma unroll
      for (int fm = 0; fm < 4; ++fm) {
        int r = wm * 64 + fm * 16 + (lane & 15);
        af[fm] = *(const bf16x8*)(((const char*)As) + r * 128 + (((kk * 4 + g) ^ (r & 7)) * 16));
      }
      #pragma unroll
      for (int fn = 0; fn < 4; ++fn) {
        int r = wn * 64 + fn * 16 + (lane & 15);
        bfr[fn] = *(const bf16x8*)(((const char*)Bs) + r * 128 + (((kk * 4 + g) ^ (r & 7)) * 16));
      }
      #pragma unroll
      for (int fm = 0; fm < 4; ++fm)
        #pragma unroll
        for (int fn = 0; fn < 4; ++fn)
          acc[fm][fn] = __builtin_amdgcn_mfma_f32_16x16x32_bf16(af[fm], bfr[fn], acc[fm][fn], 0, 0, 0);
    }
    __syncthreads();
  }

  const float TWO_L2E = 2.0f * L2E;
  #pragma unroll
  for (int fm = 0; fm < 4; ++fm)
    #pragma unroll
    for (int fn = 0; fn < 4; ++fn) {
      int gj = j0 + wn * 64 + fn * 16 + (lane & 15);
      #pragma unroll
      for (int r = 0; r < 4; ++r) {
        int gi = i0 + wm * 64 + fm * 16 + (lane >> 4) * 4 + r;
        out[(size_t)gi * N + gj] = (f16)(TWO_L2E * acc[fm][fn][r]);
      }
    }
}

// ---- persistent Sinkhorn loop + finalize
__global__ __launch_bounds__(1024, 4) void sinkhorn_persist(
    const f16* __restrict__ Z, const f16* __restrict__ ZT,
    const float* __restrict__ ax, const float* __restrict__ ay,
    float* __restrict__ fcore, float* __restrict__ gcore, float* __restrict__ php,
    unsigned* __restrict__ slots, float* __restrict__ out)
{
  __shared__ float2 part[64];
  __shared__ float sred[16];
  const int blk = blockIdx.x;
  const int t = threadIdx.x;
  const int w = t >> 6, lane = t & 63;
  const int q = w >> 2, rg = w & 3;     // wave -> column quarter q, row group rg

  // per-thread base offsets into a matrix: rows blk*16+rg*4+rr, cols q*1024+lane*16
  const size_t zoff = (size_t)(blk * 16 + rg * 4) * N + q * 1024 + lane * 16;
  const int voff = q * 1024 + lane * 16;

  f16x8 zr[4][2];
  #pragma unroll
  for (int rr = 0; rr < 4; ++rr) {
    const f16x8* zp = (const f16x8*)(Z + zoff + (size_t)rr * N);
    zr[rr][0] = zp[0]; zr[rr][1] = zp[1];
  }

  for (int ph = 0; ph < NPHASE; ++ph) {
    const bool isF = (ph & 1) == 0;
    const float* vin = isF ? gcore : fcore;
    float* vout = (ph == NPHASE - 1) ? php : (isF ? fcore : gcore);

    // fresh cross-block vector: agent-scope loads (bypass stale L2)
    float uu[16];
    #pragma unroll
    for (int k = 0; k < 16; ++k) uu[k] = ALOAD((float*)(vin + voff + k));

    #pragma unroll
    for (int rr = 0; rr < 4; ++rr) {
      float vv[16];
      #pragma unroll
      for (int k = 0; k < 8; ++k) {
        vv[k]     = uu[k]     + (float)zr[rr][0][k];
        vv[8 + k] = uu[8 + k] + (float)zr[rr][1][k];
      }
      float m = vv[0];
      #pragma unroll
      for (int k = 1; k < 16; ++k) m = fmaxf(m, vv[k]);
      #pragma unroll
      for (int o = 1; o < 64; o <<= 1) m = fmaxf(m, __shfl_xor(m, o, 64));
      float s = 0.0f;
      #pragma unroll
      for (int k = 0; k < 16; ++k) s += exp2f(vv[k] - m);
      #pragma unroll
      for (int o = 1; o < 64; o <<= 1) s += __shfl_xor(s, o, 64);
      if (lane == 0) part[(rg * 4 + rr) * 4 + q] = make_float2(m, s);
    }

    // prefetch next phase's matrix slice (plain cached loads) before the barrier
    if (ph < NPHASE - 1) {
      const f16* Mn = ((ph + 1) & 1) ? ZT : Z;
      #pragma unroll
      for (int rr = 0; rr < 4; ++rr) {
        const f16x8* zp = (const f16x8*)(Mn + zoff + (size_t)rr * N);
        zr[rr][0] = zp[0]; zr[rr][1] = zp[1];
      }
    }

    __syncthreads();
    if (t < 16) {
      float2 p0 = part[t * 4 + 0], p1 = part[t * 4 + 1], p2 = part[t * 4 + 2], p3 = part[t * 4 + 3];
      float M0 = fmaxf(fmaxf(p0.x, p1.x), fmaxf(p2.x, p3.x));
      float S0 = p0.y * exp2f(p0.x - M0) + p1.y * exp2f(p1.x - M0)
               + p2.y * exp2f(p2.x - M0) + p3.y * exp2f(p3.x - M0);
      ASTORE(&vout[blk * 16 + t], -(M0 + log2f(S0)) + LOG2A);
    }

    // ---- flag-array barrier: release own slot, poll all 256 (no L2 invalidate)
    __syncthreads();   // drains the sc1 vout stores (vmcnt(0) before s_barrier)
    if (t == 0)
      __hip_atomic_store(&slots[blk], (unsigned)(ph + 1),
                         __ATOMIC_RELEASE, __HIP_MEMORY_SCOPE_AGENT);
    if (t < 64) {
      const unsigned tgt = (unsigned)(ph + 1);
      for (;;) {
        bool ok = true;
        #pragma unroll
        for (int k = 0; k < 4; ++k)
          ok &= (ALOAD(&slots[t * 4 + k]) >= tgt);
        if (__all(ok)) break;
        __builtin_amdgcn_s_sleep(1);
      }
    }
    __syncthreads();
    asm volatile("" ::: "memory");
  }

  if (blk == 0) {
    float acc = 0.0f;
    #pragma unroll
    for (int rep = 0; rep < 4; ++rep) {
      int i = rep * 1024 + t;
      float fc = ALOAD(&fcore[i]);
      acc += exp2f(fc - ALOAD(&php[i])) * (fc + ax[i] - LOG2A);
      acc += ALOAD(&gcore[i]) + ay[i] - LOG2A;
    }
    #pragma unroll
    for (int o = 1; o < 64; o <<= 1) acc += __shfl_xor(acc, o, 64);
    if ((t & 63) == 0) sred[t >> 6] = acc;
    __syncthreads();
    if (t == 0) {
      float tot = 0.0f;
      #pragma unroll
      for (int k = 0; k < 16; ++k) tot += sred[k];
      const float LN2 = 0.6931471805599453f;
      out[0] = tot * (LN2 / ((float)N * (float)D));
    }
  }
}

extern "C" void kernel_launch(void* const* d_in, const int* in_sizes, int n_in,
                              void* d_out, int out_size, void* d_ws, size_t ws_size,
                              hipStream_t stream) {
  const float* x = (const float*)d_in[0];
  const float* y = (const float*)d_in[1];
  float* out = (float*)d_out;
  char* ws = (char*)d_ws;

  const size_t SZ_Z  = (size_t)N * N * sizeof(f16);   // 32 MiB
  const size_t SZ_BF = (size_t)N * D * sizeof(u16);   // 8 MiB
  const size_t SZ_V  = (size_t)N * sizeof(float);     // 16 KiB

  f16* Z   = (f16*)(ws);
  f16* ZT  = (f16*)(ws + SZ_Z);
  u16* xb  = (u16*)(ws + 2 * SZ_Z);
  u16* yb  = (u16*)(ws + 2 * SZ_Z + SZ_BF);
  char* vb = ws + 2 * SZ_Z + 2 * SZ_BF;
  float* ax    = (float*)(vb + 0 * SZ_V);
  float* ay    = (float*)(vb + 1 * SZ_V);
  float* fcore = (float*)(vb + 2 * SZ_V);
  float* gcore = (float*)(vb + 3 * SZ_V);
  float* php   = (float*)(vb + 4 * SZ_V);
  unsigned* slots = (unsigned*)(vb + 5 * SZ_V);

  prep_kernel<<<2 * N, 256, 0, stream>>>(x, y, xb, yb, ax, ay, gcore, slots);

  dim3 gg(N / 128, N / 128, 1);
  gemm_s<<<gg, 256, 0, stream>>>(xb, yb, Z);
  gemm_s<<<gg, 256, 0, stream>>>(yb, xb, ZT);

  sinkhorn_persist<<<NBLK, 1024, 0, stream>>>(Z, ZT, ax, ay, fcore, gcore, php, slots, out);
}

// Round 5
// 2168.570 us; speedup vs baseline: 3.6286x; 2.3525x over previous
//
#include <hip/hip_runtime.h>
#include <hip/hip_bf16.h>

// Sinkhorn entropic OT (reg=1, 100 iters), persistent kernel + DATAFLOW sync.
//   Z = 2*log2e*(x.yT) fp16 [32MiB], ZT likewise. Cores telescope:
//   f: fcore_i = LOG2A - log2 sum_j 2^(gcore_j + Z_ij)     (even phases)
//   g: gcore_j = LOG2A - log2 sum_i 2^(fcore_i + ZT_ji)    (odd phases)
//   init gcore_j = LOG2A - ay_j
// Sync: each core value is an 8-byte slot (tag<<32 | float bits), relaxed
// AGENT-scope atomics (sc1 -> L3, bypasses non-coherent L2s). Phase ph spins
// for tag==ph on its inputs, publishes tag=ph+1. All-to-all dependency per
// phase => max skew < 2 phases => single buffer is race-free. No grid barrier,
// no acquire/release, no vmcnt-draining fences in the loop.
// out = ln2/(N*D) * [ sum_i 2^(fcore-php)*(fcore+ax-LOG2A) + sum_j (gcore+ay-LOG2A) ]

#define N 4096
#define D 1024
#define L2E 1.4426950408889634f
#define LOG2A (-12.0f)
#define NBLK 256
#define NPHASE 201   // 100*(f,g) + final f (row marginals)

typedef unsigned short u16;
typedef unsigned long long u64;
typedef _Float16 f16;
typedef __attribute__((ext_vector_type(8))) short bf16x8;
typedef __attribute__((ext_vector_type(8))) _Float16 f16x8;
typedef __attribute__((ext_vector_type(4))) float f32x4;

#define ALOAD64(p)     __hip_atomic_load((p), __ATOMIC_RELAXED, __HIP_MEMORY_SCOPE_AGENT)
#define ASTORE64(p, v) __hip_atomic_store((p), (v), __ATOMIC_RELAXED, __HIP_MEMORY_SCOPE_AGENT)

static __device__ inline u64 pack(unsigned tag, float v) {
  return ((u64)tag << 32) | (u64)__float_as_uint(v);
}

static __device__ inline float spin_load(const u64* p, unsigned want) {
  u64 v = ALOAD64(p);
  while ((unsigned)(v >> 32) != want) {
    __builtin_amdgcn_s_sleep(1);
    v = ALOAD64(p);
  }
  return __uint_as_float((unsigned)v);
}

static __device__ inline u16 f2bf(float f) {
  unsigned u = __float_as_uint(f);
  unsigned r = (u + 0x7FFFu + ((u >> 16) & 1u)) >> 16;
  return (u16)r;
}

static __device__ inline void gload_lds16(const void* g, void* l) {
  __builtin_amdgcn_global_load_lds(
      (const __attribute__((address_space(1))) void*)g,
      (__attribute__((address_space(3))) void*)l, 16, 0, 0);
}

// ---- prep: row sum-of-squares + fp32->bf16 + ax/ay + slot init (replay-safe)
__global__ __launch_bounds__(256) void prep_kernel(
    const float* __restrict__ x, const float* __restrict__ y,
    u16* __restrict__ xb, u16* __restrict__ yb,
    float* __restrict__ ax, float* __restrict__ ay,
    u64* __restrict__ fsl, u64* __restrict__ gsl, u64* __restrict__ psl)
{
  int rb = blockIdx.x;
  bool isY = rb >= N;
  int row = isY ? rb - N : rb;
  const float4* src = (const float4*)((isY ? y : x) + (size_t)row * D);
  u16* dst = (isY ? yb : xb) + (size_t)row * D;
  int t = threadIdx.x;

  if (!isY && t == 0) {            // reset tags every call (graph-replay safe)
    ASTORE64(&fsl[row], 0ull);
    ASTORE64(&psl[row], 0ull);
  }

  float4 v = src[t];
  float ss = v.x * v.x + v.y * v.y + v.z * v.z + v.w * v.w;
  ushort4 h;
  h.x = f2bf(v.x); h.y = f2bf(v.y); h.z = f2bf(v.z); h.w = f2bf(v.w);
  ((ushort4*)dst)[t] = h;

  #pragma unroll
  for (int o = 1; o < 64; o <<= 1) ss += __shfl_xor(ss, o, 64);
  __shared__ float sred[4];
  if ((t & 63) == 0) sred[t >> 6] = ss;
  __syncthreads();
  if (t == 0) {
    float a = (sred[0] + sred[1] + sred[2] + sred[3]) * L2E;
    if (isY) { ay[row] = a; ASTORE64(&gsl[row], pack(0u, LOG2A - a)); }
    else     { ax[row] = a; }
  }
}

// ---- GEMM: Z[i][j] = fp16(2*log2e*(A_i . B_j)), bf16 MFMA 128x128 tile
__global__ __launch_bounds__(256) void gemm_s(
    const u16* __restrict__ A, const u16* __restrict__ B, f16* __restrict__ out)
{
  __shared__ u16 As[128 * 64];
  __shared__ u16 Bs[128 * 64];
  const int t = threadIdx.x;
  const int lane = t & 63, w = t >> 6;
  const int wm = w >> 1, wn = w & 1;
  const int i0 = blockIdx.y * 128, j0 = blockIdx.x * 128;

  f32x4 acc[4][4] = {};

  for (int k0 = 0; k0 < D; k0 += 64) {
    #pragma unroll
    for (int q = 0; q < 4; ++q) {
      int lin = q * 256 + t;
      int row = lin >> 3, c8 = lin & 7;
      int cs = c8 ^ (row & 7);
      gload_lds16(A + (size_t)(i0 + row) * D + k0 + cs * 8, ((char*)As) + q * 4096 + w * 1024);
      gload_lds16(B + (size_t)(j0 + row) * D + k0 + cs * 8, ((char*)Bs) + q * 4096 + w * 1024);
    }
    __syncthreads();
    #pragma unroll
    for (int kk = 0; kk < 2; ++kk) {
      bf16x8 af[4], bfr[4];
      const int g = lane >> 4;
      #pragma unroll
      for (int fm = 0; fm < 4; ++fm) {
        int r = wm * 64 + fm * 16 + (lane & 15);
        af[fm] = *(const bf16x8*)(((const char*)As) + r * 128 + (((kk * 4 + g) ^ (r & 7)) * 16));
      }
      #pragma unroll
      for (int fn = 0; fn < 4; ++fn) {
        int r = wn * 64 + fn * 16 + (lane & 15);
        bfr[fn] = *(const bf16x8*)(((const char*)Bs) + r * 128 + (((kk * 4 + g) ^ (r & 7)) * 16));
      }
      #pragma unroll
      for (int fm = 0; fm < 4; ++fm)
        #pragma unroll
        for (int fn = 0; fn < 4; ++fn)
          acc[fm][fn] = __builtin_amdgcn_mfma_f32_16x16x32_bf16(af[fm], bfr[fn], acc[fm][fn], 0, 0, 0);
    }
    __syncthreads();
  }

  const float TWO_L2E = 2.0f * L2E;
  #pragma unroll
  for (int fm = 0; fm < 4; ++fm)
    #pragma unroll
    for (int fn = 0; fn < 4; ++fn) {
      int gj = j0 + wn * 64 + fn * 16 + (lane & 15);
      #pragma unroll
      for (int r = 0; r < 4; ++r) {
        int gi = i0 + wm * 64 + fm * 16 + (lane >> 4) * 4 + r;
        out[(size_t)gi * N + gj] = (f16)(TWO_L2E * acc[fm][fn][r]);
      }
    }
}

// ---- persistent Sinkhorn, row-per-wave, dataflow-synced
__global__ __launch_bounds__(1024, 4) void sinkhorn_persist(
    const f16* __restrict__ Z, const f16* __restrict__ ZT,
    const float* __restrict__ ax, const float* __restrict__ ay,
    u64* __restrict__ fsl, u64* __restrict__ gsl, u64* __restrict__ psl,
    float* __restrict__ out)
{
  __shared__ float uu[N];
  __shared__ float sred[16];
  const int t = threadIdx.x, blk = blockIdx.x;
  const int w = t >> 6, lane = t & 63;
  const int row = blk * 16 + w;                       // wave w owns row `row`
  const size_t zbase = (size_t)row * N + (lane << 3); // + c*512 per chunk

  for (int ph = 0; ph < NPHASE; ++ph) {
    const f16* M  = (ph & 1) ? ZT : Z;
    const u64* vin = (ph & 1) ? fsl : gsl;
    u64* vsl = (ph == NPHASE - 1) ? psl : ((ph & 1) ? gsl : fsl);

    // issue this phase's matrix loads first (independent of dataflow)
    f16x8 z[8];
    #pragma unroll
    for (int c = 0; c < 8; ++c)
      z[c] = *(const f16x8*)(M + zbase + (size_t)(c << 9));

    // cooperative spin-stage of the 4096 input cores into LDS
    #pragma unroll
    for (int k = 0; k < 4; ++k) {
      int col = (t << 2) | k;
      uu[col] = spin_load(&vin[col], (unsigned)ph);
    }
    __syncthreads();

    // two half-row passes (register pressure), per-lane (m,s)
    float m1 = -3.0e38f, s1 = 0.0f, m2 = -3.0e38f, s2 = 0.0f;
    {
      float vv[32];
      #pragma unroll
      for (int c = 0; c < 4; ++c)
        #pragma unroll
        for (int j = 0; j < 8; ++j) {
          float val = uu[(c << 9) + (lane << 3) + j] + (float)z[c][j];
          vv[(c << 3) | j] = val;
          m1 = fmaxf(m1, val);
        }
      #pragma unroll
      for (int k = 0; k < 32; ++k) s1 += exp2f(vv[k] - m1);
    }
    {
      float vv[32];
      #pragma unroll
      for (int c = 4; c < 8; ++c)
        #pragma unroll
        for (int j = 0; j < 8; ++j) {
          float val = uu[(c << 9) + (lane << 3) + j] + (float)z[c][j];
          vv[((c - 4) << 3) | j] = val;
          m2 = fmaxf(m2, val);
        }
      #pragma unroll
      for (int k = 0; k < 32; ++k) s2 += exp2f(vv[k] - m2);
    }
    float m = fmaxf(m1, m2);
    float s = s1 * exp2f(m1 - m) + s2 * exp2f(m2 - m);

    #pragma unroll
    for (int o = 1; o < 64; o <<= 1) {
      float mo = __shfl_xor(m, o, 64);
      float so = __shfl_xor(s, o, 64);
      float mn = fmaxf(m, mo);
      s = s * exp2f(m - mn) + so * exp2f(mo - mn);
      m = mn;
    }
    if (lane == 0)
      ASTORE64(&vsl[row], pack((unsigned)(ph + 1), LOG2A - (m + log2f(s))));
    __syncthreads();   // protect uu reuse next phase
  }

  // finalize: block 0 gathers (spins until every block's last outputs land)
  if (blk == 0) {
    float acc = 0.0f;
    #pragma unroll
    for (int rep = 0; rep < 4; ++rep) {
      int i = (rep << 10) + t;
      float fc = spin_load(&fsl[i], (unsigned)(NPHASE - 2));  // tag 199
      float gc = spin_load(&gsl[i], (unsigned)(NPHASE - 1));  // tag 200
      float pp = spin_load(&psl[i], (unsigned)NPHASE);        // tag 201
      acc += exp2f(fc - pp) * (fc + ax[i] - LOG2A);
      acc += gc + ay[i] - LOG2A;
    }
    #pragma unroll
    for (int o = 1; o < 64; o <<= 1) acc += __shfl_xor(acc, o, 64);
    if ((t & 63) == 0) sred[t >> 6] = acc;
    __syncthreads();
    if (t == 0) {
      float tot = 0.0f;
      #pragma unroll
      for (int k = 0; k < 16; ++k) tot += sred[k];
      const float LN2 = 0.6931471805599453f;
      out[0] = tot * (LN2 / ((float)N * (float)D));
    }
  }
}

extern "C" void kernel_launch(void* const* d_in, const int* in_sizes, int n_in,
                              void* d_out, int out_size, void* d_ws, size_t ws_size,
                              hipStream_t stream) {
  const float* x = (const float*)d_in[0];
  const float* y = (const float*)d_in[1];
  float* out = (float*)d_out;
  char* ws = (char*)d_ws;

  const size_t SZ_Z  = (size_t)N * N * sizeof(f16);   // 32 MiB
  const size_t SZ_BF = (size_t)N * D * sizeof(u16);   // 8 MiB
  const size_t SZ_V  = (size_t)N * sizeof(float);     // 16 KiB
  const size_t SZ_S  = (size_t)N * sizeof(u64);       // 32 KiB

  f16* Z   = (f16*)(ws);
  f16* ZT  = (f16*)(ws + SZ_Z);
  u16* xb  = (u16*)(ws + 2 * SZ_Z);
  u16* yb  = (u16*)(ws + 2 * SZ_Z + SZ_BF);
  char* vb = ws + 2 * SZ_Z + 2 * SZ_BF;
  float* ax = (float*)(vb + 0 * SZ_V);
  float* ay = (float*)(vb + 1 * SZ_V);
  u64* fsl  = (u64*)(vb + 2 * SZ_V);
  u64* gsl  = (u64*)(vb + 2 * SZ_V + 1 * SZ_S);
  u64* psl  = (u64*)(vb + 2 * SZ_V + 2 * SZ_S);

  prep_kernel<<<2 * N, 256, 0, stream>>>(x, y, xb, yb, ax, ay, fsl, gsl, psl);

  dim3 gg(N / 128, N / 128, 1);
  gemm_s<<<gg, 256, 0, stream>>>(xb, yb, Z);
  gemm_s<<<gg, 256, 0, stream>>>(yb, xb, ZT);

  sinkhorn_persist<<<NBLK, 1024, 0, stream>>>(Z, ZT, ax, ay, fsl, gsl, psl, out);
}